// Round 5
// baseline (607.771 us; speedup 1.0000x reference)
//
#include <hip/hip_runtime.h>

// Problem: B=64, T=512, C=64, K=64
//   x:        [B,T,C]  f32   (2,097,152 elems, 8 MiB)
//   evaluate: [C,K]    f32   (4096 elems, 16 KiB, per-channel sorted centers)
//   focus:    [C,K]    f32   (4096 elems, 16 KiB)
//   out:      [B,T,C*K] f32  (134,217,728 elems, 512 MiB)  -> write-BW bound
//
// Per row r=(b,t,c): d_k=|x-e_k|; idx=argmin d; f=focus[c][idx];
//   softmax(-d*f) = exp(-(d_k-dmin)*f)/sum  (max of -d*f is at argmin since f>0)
//
// Mapping: 16 lanes per row, 4 k's (one float4) per lane.
//   - wave covers 4 consecutive rows -> 1 KiB contiguous evaluate load,
//     1 KiB contiguous nontemporal store per instruction.
//   - argmin/sum reduces: 4 shfl_xor steps (masks 1,2,4,8 stay in 16-lane group).

typedef float f32x4 __attribute__((ext_vector_type(4)));

#define ROWS (64 * 512 * 64)   // B*T*C = 2,097,152
#define CMASK 63               // C = 64
#define LOG2E 1.44269504088896340736f

__global__ __launch_bounds__(256, 8)
void softquant_kernel(const float* __restrict__ x,
                      const float* __restrict__ evaluate,
                      const float* __restrict__ focus,
                      float* __restrict__ out) {
    const int total  = ROWS * 16;                       // 33,554,432 work items
    const int stride = gridDim.x * blockDim.x;          // 524,288
    int g = blockIdx.x * blockDim.x + threadIdx.x;

    for (; g < total; g += stride) {
        const int row = g >> 4;        // flattened (b,t,c)
        const int k0  = (g & 15) << 2; // this lane's first k (0,4,...,60)
        const int c   = row & CMASK;   // channel
        const int cb  = c << 6;        // channel base into [C,K] tables

        const float xv = x[row];       // 16-way broadcast load (L1/L2 hit)
        const f32x4 ev = *reinterpret_cast<const f32x4*>(evaluate + cb + k0);

        const float d0 = fabsf(xv - ev.x);
        const float d1 = fabsf(xv - ev.y);
        const float d2 = fabsf(xv - ev.z);
        const float d3 = fabsf(xv - ev.w);

        // local argmin, first-min-wins (matches jnp.argmin tie-break)
        float dmin = d0; int idx = k0;
        if (d1 < dmin) { dmin = d1; idx = k0 + 1; }
        if (d2 < dmin) { dmin = d2; idx = k0 + 2; }
        if (d3 < dmin) { dmin = d3; idx = k0 + 3; }

        // cross-lane argmin over the 16-lane group (xor masks < 16 stay in-group)
        #pragma unroll
        for (int m = 1; m < 16; m <<= 1) {
            const float dm = __shfl_xor(dmin, m);
            const int   im = __shfl_xor(idx,  m);
            if (dm < dmin || (dm == dmin && im < idx)) { dmin = dm; idx = im; }
        }

        const float f  = focus[cb + idx];   // broadcast gather (cached)
        const float fl = f * LOG2E;         // fold ln2 into the scale

        const float s0 = exp2f((dmin - d0) * fl);
        const float s1 = exp2f((dmin - d1) * fl);
        const float s2 = exp2f((dmin - d2) * fl);
        const float s3 = exp2f((dmin - d3) * fl);

        float ssum = (s0 + s1) + (s2 + s3);
        #pragma unroll
        for (int m = 1; m < 16; m <<= 1) ssum += __shfl_xor(ssum, m);

        const float inv = 1.0f / ssum;      // exact div (no fast-math surprises)

        f32x4 o;
        o.x = s0 * inv; o.y = s1 * inv; o.z = s2 * inv; o.w = s3 * inv;

        // lanes 0..63 write 16B each, contiguous 1 KiB, write-once -> nontemporal
        f32x4* dst = reinterpret_cast<f32x4*>(out + ((long long)row << 6) + k0);
        __builtin_nontemporal_store(o, dst);
    }
}

extern "C" void kernel_launch(void* const* d_in, const int* in_sizes, int n_in,
                              void* d_out, int out_size, void* d_ws, size_t ws_size,
                              hipStream_t stream) {
    const float* x        = (const float*)d_in[0];
    const float* evaluate = (const float*)d_in[1];
    const float* focus    = (const float*)d_in[2];
    float* out            = (float*)d_out;

    // 2048 blocks * 256 threads = 8 blocks/CU on 256 CUs, 64 grid-stride iters
    hipLaunchKernelGGL(softquant_kernel, dim3(2048), dim3(256), 0, stream,
                       x, evaluate, focus, out);
}

// Round 8
// 592.995 us; speedup vs baseline: 1.0249x; 1.0249x over previous
//
#include <hip/hip_runtime.h>

// Problem: B=64, T=512, C=64, K=64
//   x:[B,T,C] f32 (8 MiB); evaluate,focus:[C,K] f32 (16 KiB each)
//   out:[B,T,C*K] f32 (512 MiB)  -> write-BW bound (fill kernel proves 6.25 TB/s)
//
// R5 post-mortem: single-kernel version ran ~263 us (~2.1 TB/s) — the per-
// iteration dependent chain (x load -> 4-step shuffle argmin -> focus gather
// -> exp -> 4-step shuffle sum -> exact div -> store) throttled the store
// stream. Split-phase fix:
//   Phase 1 (per row, 2M): wave-uniform channel => scalar table loads, NO
//     shuffles; computes m=dmin, fl=focus[argmin]*log2e, inv=1/sum; writes
//     SoA transposed (coalesced) into d_ws (24 MiB).
//   Phase 2 (per elem, 134M): pure streaming: broadcast loads + 6 VALU/elem,
//     compile-time trip count for unroll/ILP, NT float4 stores.
// Expressions kept bit-identical to the R5-passing kernel.

typedef float f32x4 __attribute__((ext_vector_type(4)));

#define B_ 64
#define T_ 512
#define C_ 64
#define K_ 64
#define ROWS (B_ * T_ * C_)     // 2,097,152
#define BT   (B_ * T_)          // 32,768
#define LOG2E 1.44269504088896340736f

// ---------------- Phase 1: per-row stats ----------------
// task w (0..32767) = one wave: channel c = w&63 (wave-uniform),
// bt-chunk base = (w>>6)*64; lane l handles bt = base+l, row = bt*64+c.
// Stats stored at tr = c*BT + bt -> consecutive per wave (coalesced).
__global__ __launch_bounds__(256, 4)
void stats_kernel(const float* __restrict__ x,
                  const float* __restrict__ evaluate,
                  const float* __restrict__ focus,
                  float* __restrict__ ws) {
    float* __restrict__ ws_m   = ws;
    float* __restrict__ ws_fl  = ws + ROWS;
    float* __restrict__ ws_inv = ws + 2 * ROWS;

    const int lane = threadIdx.x & 63;
    const int w    = blockIdx.x * 4 + (threadIdx.x >> 6);     // 8192 blocks * 4 waves
    const int c    = __builtin_amdgcn_readfirstlane(w & 63);  // force wave-uniform
    const int btb  = __builtin_amdgcn_readfirstlane((w >> 6) << 6);
    const int bt   = btb + lane;

    const float xv = x[bt * 64 + c];
    const float* __restrict__ ev = evaluate + (c << 6);       // scalar base

    // argmin, first-min-wins (matches jnp.argmin)
    float dmin = fabsf(xv - ev[0]);
    int   idx  = 0;
    #pragma unroll
    for (int k = 1; k < 64; ++k) {
        const float d = fabsf(xv - ev[k]);
        if (d < dmin) { dmin = d; idx = k; }
    }

    const float f  = focus[(c << 6) + idx];   // per-lane gather within 256 B (L1)
    const float fl = f * LOG2E;

    float sum = 0.0f;
    #pragma unroll
    for (int k = 0; k < 64; ++k) {
        const float d = fabsf(xv - ev[k]);    // bitwise same d as above
        sum += exp2f((dmin - d) * fl);
    }
    const float inv = 1.0f / sum;             // exact div, once per row

    const int tr = c * BT + bt;
    ws_m[tr] = dmin; ws_fl[tr] = fl; ws_inv[tr] = inv;
}

// ---------------- Phase 2: streaming expand ----------------
// 2048 blocks * 256 thr * 64 iters = 33,554,432 float4-items (compile-time).
__global__ __launch_bounds__(256, 4)
void expand_kernel(const float* __restrict__ x,
                   const float* __restrict__ evaluate,
                   const float* __restrict__ ws,
                   float* __restrict__ out) {
    const float* __restrict__ ws_m   = ws;
    const float* __restrict__ ws_fl  = ws + ROWS;
    const float* __restrict__ ws_inv = ws + 2 * ROWS;

    const int base = blockIdx.x * 256 + threadIdx.x;

    #pragma unroll 4
    for (int it = 0; it < 64; ++it) {
        const int g   = base + it * (2048 * 256);
        const int row = g >> 4;                 // (b,t,c) flattened
        const int k0  = (g & 15) << 2;          // lane's first k
        const int c   = row & 63;
        const int tr  = c * BT + (row >> 6);    // transposed stats index

        const float xv  = x[row];               // broadcast (L2)
        const float m   = ws_m[tr];             // broadcast (L2)
        const float fl  = ws_fl[tr];
        const float inv = ws_inv[tr];
        const f32x4 e   = *reinterpret_cast<const f32x4*>(evaluate + (c << 6) + k0);

        f32x4 o;
        o.x = exp2f((m - fabsf(xv - e.x)) * fl) * inv;
        o.y = exp2f((m - fabsf(xv - e.y)) * fl) * inv;
        o.z = exp2f((m - fabsf(xv - e.z)) * fl) * inv;
        o.w = exp2f((m - fabsf(xv - e.w)) * fl) * inv;

        f32x4* dst = reinterpret_cast<f32x4*>(out + ((long long)row << 6) + k0);
        __builtin_nontemporal_store(o, dst);    // write-once, 1 KiB/wave contiguous
    }
}

// ---------------- Fallback (R5 kernel) if ws is too small ----------------
__global__ __launch_bounds__(256, 8)
void softquant_kernel(const float* __restrict__ x,
                      const float* __restrict__ evaluate,
                      const float* __restrict__ focus,
                      float* __restrict__ out) {
    const int total  = ROWS * 16;
    const int stride = gridDim.x * blockDim.x;
    int g = blockIdx.x * blockDim.x + threadIdx.x;
    for (; g < total; g += stride) {
        const int row = g >> 4;
        const int k0  = (g & 15) << 2;
        const int c   = row & 63;
        const int cb  = c << 6;
        const float xv = x[row];
        const f32x4 ev = *reinterpret_cast<const f32x4*>(evaluate + cb + k0);
        const float d0 = fabsf(xv - ev.x);
        const float d1 = fabsf(xv - ev.y);
        const float d2 = fabsf(xv - ev.z);
        const float d3 = fabsf(xv - ev.w);
        float dmin = d0; int idx = k0;
        if (d1 < dmin) { dmin = d1; idx = k0 + 1; }
        if (d2 < dmin) { dmin = d2; idx = k0 + 2; }
        if (d3 < dmin) { dmin = d3; idx = k0 + 3; }
        #pragma unroll
        for (int m = 1; m < 16; m <<= 1) {
            const float dm = __shfl_xor(dmin, m);
            const int   im = __shfl_xor(idx,  m);
            if (dm < dmin || (dm == dmin && im < idx)) { dmin = dm; idx = im; }
        }
        const float f  = focus[cb + idx];
        const float fl = f * LOG2E;
        const float s0 = exp2f((dmin - d0) * fl);
        const float s1 = exp2f((dmin - d1) * fl);
        const float s2 = exp2f((dmin - d2) * fl);
        const float s3 = exp2f((dmin - d3) * fl);
        float ssum = (s0 + s1) + (s2 + s3);
        #pragma unroll
        for (int m = 1; m < 16; m <<= 1) ssum += __shfl_xor(ssum, m);
        const float inv = 1.0f / ssum;
        f32x4 o;
        o.x = s0 * inv; o.y = s1 * inv; o.z = s2 * inv; o.w = s3 * inv;
        f32x4* dst = reinterpret_cast<f32x4*>(out + ((long long)row << 6) + k0);
        __builtin_nontemporal_store(o, dst);
    }
}

extern "C" void kernel_launch(void* const* d_in, const int* in_sizes, int n_in,
                              void* d_out, int out_size, void* d_ws, size_t ws_size,
                              hipStream_t stream) {
    const float* x        = (const float*)d_in[0];
    const float* evaluate = (const float*)d_in[1];
    const float* focus    = (const float*)d_in[2];
    float* out            = (float*)d_out;

    if (ws_size >= (size_t)3 * ROWS * sizeof(float)) {
        float* ws = (float*)d_ws;
        // Phase 1: 32768 wave-tasks = 8192 blocks * 4 waves (exact)
        hipLaunchKernelGGL(stats_kernel, dim3(8192), dim3(256), 0, stream,
                           x, evaluate, focus, ws);
        // Phase 2: 2048 blocks * 256 thr * 64 iters (exact, compile-time)
        hipLaunchKernelGGL(expand_kernel, dim3(2048), dim3(256), 0, stream,
                           x, evaluate, ws, out);
    } else {
        hipLaunchKernelGGL(softquant_kernel, dim3(2048), dim3(256), 0, stream,
                           x, evaluate, focus, out);
    }
}